// Round 10
// baseline (404.176 us; speedup 1.0000x reference)
//
#include <hip/hip_runtime.h>
#include <math.h>

// ---------------------------------------------------------------------------
// GCN: h1 = relu(norm_agg(x@W1)+b1); h2 = norm_agg(h1@W2)+b2;
//      g = mean_pool(h2, batch); out = relu(g@W3+b3)@W4 + b4
// norm_agg(h)[d] = (sum_{e: dst=d} h[src]*dinv[src] + h[d]*dinv[d]) * dinv[d]
// Build (16-node blocks, block-granular only): LDS histogram over 6250
// dst-blocks -> 1-block scan -> two-level line-dense scatter (98 buckets of
// 1024 nodes, then 64 blocks/bucket) -> per-block src sort (+deg -> dinv).
// Aggregation: wave owns 16 dsts (4 KB LDS acc), sweeps its src-sorted
// segment (collective L2-resident front) with a DOUBLE-BUFFERED gather
// pipeline (round r+1's 16 gathers in flight while accumulating round r).
// GEMM epilogue pre-scales rows by dinv. Graph node-counts via binary search.
// Entry packing: (dstLow6<<21) | (src<<4) | dstLocal4; csr strips dstLow6.
// ---------------------------------------------------------------------------

__global__ __launch_bounds__(256) void k_init(float* gsum, int* blockCnt,
                                              int gsz, int nz) {
  int i = blockIdx.x * 256 + threadIdx.x;
  if (i < gsz) gsum[i] = 0.f;
  if (i < nz) blockCnt[i] = 0;
}

// Histogram of dst>>4 into nblk bins via LDS (25.6 KB), merged to global.
__global__ __launch_bounds__(256) void k_histB(const int* __restrict__ dst,
                                               int* __restrict__ blockCnt,
                                               int e, int nblk) {
  __shared__ int h[6400];
  int t = threadIdx.x;
  for (int i = t; i < 6400; i += 256) h[i] = 0;
  __syncthreads();
  int base = blockIdx.x * 8192;
#pragma unroll
  for (int k = 0; k < 32; ++k) {
    int i = base + k * 256 + t;
    if (i < e) atomicAdd(&h[dst[i] >> 4], 1);
  }
  __syncthreads();
  for (int i = t; i < nblk; i += 256) {
    int v = h[i];
    if (v) atomicAdd(&blockCnt[i], v);
  }
}

// Single-block exclusive scan of blockCnt[nblk]; writes blockBase (nblk+1),
// blockCursor (=base), bucketCursor (every 64th block).
__global__ __launch_bounds__(256) void k_scan(const int* __restrict__ blockCnt,
                                              int* __restrict__ blockBase,
                                              int* __restrict__ blockCursor,
                                              int* __restrict__ bucketCursor,
                                              int nblk, int nbuck) {
  __shared__ int sh[256];
  __shared__ int carry;
  int t = threadIdx.x;
  if (t == 0) carry = 0;
  __syncthreads();
  int nchunk = (nblk + 255) / 256;
  for (int ch = 0; ch < nchunk; ++ch) {
    int idx = ch * 256 + t;
    int v = (idx < nblk) ? blockCnt[idx] : 0;
    sh[t] = v;
    __syncthreads();
    for (int off = 1; off < 256; off <<= 1) {
      int x = (t >= off) ? sh[t - off] : 0;
      __syncthreads();
      sh[t] += x;
      __syncthreads();
    }
    int base = carry;
    int b = base + sh[t] - v;
    if (idx < nblk) {
      blockBase[idx] = b;
      blockCursor[idx] = b;
      if ((idx & 63) == 0 && (idx >> 6) < nbuck) bucketCursor[idx >> 6] = b;
    }
    __syncthreads();
    if (t == 255) carry = base + sh[255];
    __syncthreads();
  }
  if (t == 0) blockBase[nblk] = carry;  // total = e
}

// Pass 1: bin edges into coarse buckets (1024 nodes each) with range-dense
// writes. Entry = (dstLow6<<21) | (src<<4) | dstLocal4.
__global__ __launch_bounds__(256) void k_p1(const int* __restrict__ src,
                                            const int* __restrict__ dst,
                                            int* __restrict__ bucketCursor,
                                            int* __restrict__ tmp, int e,
                                            int nbuck) {
  __shared__ int hist[128];
  __shared__ int gbase[128];
  int t = threadIdx.x;
  int base = blockIdx.x * 2048;
  if (t < 128) hist[t] = 0;
  __syncthreads();
  int ent[8], rk[8], bk[8];
#pragma unroll
  for (int k = 0; k < 8; ++k) {
    int i = base + k * 256 + t;
    bool v = i < e;
    int s = v ? src[i] : 0;
    int d = v ? dst[i] : 0;
    bk[k] = d >> 10;
    ent[k] = (((d >> 4) & 63) << 21) | (s << 4) | (d & 15);
    rk[k] = v ? atomicAdd(&hist[bk[k]], 1) : -1;
  }
  __syncthreads();
  if (t < nbuck && hist[t] > 0) gbase[t] = atomicAdd(&bucketCursor[t], hist[t]);
  __syncthreads();
#pragma unroll
  for (int k = 0; k < 8; ++k)
    if (rk[k] >= 0) tmp[gbase[bk[k]] + rk[k]] = ent[k];
}

// Pass 2: within each bucket (8 slices/bucket), bin entries to their dst-block
// segment (64 bins), range-dense writes; strip top 6 bits for final csr.
__global__ __launch_bounds__(256) void k_p2(const int* __restrict__ blockBase,
                                            const int* __restrict__ tmp,
                                            int* __restrict__ blockCursor,
                                            int* __restrict__ csr, int nblk) {
  __shared__ int hist[64];
  __shared__ int gbase[64];
  int b = blockIdx.x >> 3;
  int sl = blockIdx.x & 7;
  int hiIdx = (b + 1) << 6;
  if (hiIdx > nblk) hiIdx = nblk;
  int lo_b = blockBase[b << 6];
  int hi_b = blockBase[hiIdx];
  int len = hi_b - lo_b;
  int lo = lo_b + (int)(((long long)len * sl) >> 3);
  int hi = lo_b + (int)(((long long)len * (sl + 1)) >> 3);
  int t = threadIdx.x;
  for (int rbase = lo; rbase < hi; rbase += 2048) {
    if (t < 64) hist[t] = 0;
    __syncthreads();
    int ent[8], rk[8], bin[8];
#pragma unroll
    for (int k = 0; k < 8; ++k) {
      int i = rbase + k * 256 + t;
      bool v = i < hi;
      int en = v ? tmp[i] : 0;
      ent[k] = en;
      bin[k] = en >> 21;  // 6 bits, entry has 27 bits total
      rk[k] = v ? atomicAdd(&hist[bin[k]], 1) : -1;
    }
    __syncthreads();
    if (t < 64 && hist[t] > 0)
      gbase[t] = atomicAdd(&blockCursor[(b << 6) + t], hist[t]);
    __syncthreads();
#pragma unroll
    for (int k = 0; k < 8; ++k)
      if (rk[k] >= 0) csr[gbase[bin[k]] + rk[k]] = ent[k] & 0x1FFFFF;
    __syncthreads();
  }
}

// Per-16-node block: count degrees -> dinv, then counting-sort the packed
// segment by src>>11 (locality-only; skipped for oversize segments).
__global__ __launch_bounds__(256) void k_bsort(const int* __restrict__ blockBase,
                                               int* __restrict__ csr,
                                               float* __restrict__ dinv, int n) {
  __shared__ int in_sh[1024];
  __shared__ int out_sh[1024];
  __shared__ int hist[64];
  __shared__ int hscan[64];
  __shared__ int deg[16];
  int blk = blockIdx.x;
  int nodeBase = blk << 4;
  if (nodeBase >= n) return;
  int p0 = blockBase[blk];
  int p1 = blockBase[blk + 1];
  int seg = p1 - p0;
  int t = threadIdx.x;
  if (t < 16) deg[t] = 0;
  __syncthreads();
  for (int i = t; i < seg; i += 256) atomicAdd(&deg[csr[p0 + i] & 15], 1);
  __syncthreads();
  if (t < 16 && nodeBase + t < n)
    dinv[nodeBase + t] = 1.0f / sqrtf((float)(deg[t] + 1));
  if (seg <= 0 || seg > 1024) return;  // block-uniform
  if (t < 64) hist[t] = 0;
  __syncthreads();
  for (int i = t; i < seg; i += 256) {
    int v = csr[p0 + i];
    in_sh[i] = v;
    atomicAdd(&hist[v >> 15], 1);  // (src<<4)>>15 == src>>11, <= 48
  }
  __syncthreads();
  if (t == 0) {
    int s = 0;
    for (int b = 0; b < 64; ++b) {
      hscan[b] = s;
      s += hist[b];
    }
  }
  __syncthreads();
  for (int i = t; i < seg; i += 256) {
    int v = in_sh[i];
    int pos = atomicAdd(&hscan[v >> 15], 1);
    out_sh[pos] = v;
  }
  __syncthreads();
  for (int i = t; i < seg; i += 256) csr[p0 + i] = out_sh[i];
}

// Y[N,64] = (X[N,64] @ W[64,64]) * dinv[row]  (row-scaled epilogue).
__global__ __launch_bounds__(256) void k_gemm64s(const float* __restrict__ X,
                                                 const float* __restrict__ W,
                                                 const float* __restrict__ dinv,
                                                 float* __restrict__ Y, int n) {
  __shared__ float Xs[64 * 65];
  __shared__ float Ws[64 * 64];
  int t = threadIdx.x;
  int r0 = blockIdx.x << 6;
  for (int i = t * 4; i < 4096; i += 1024)
    *(float4*)&Ws[i] = *(const float4*)&W[i];
  for (int s = t; s < 1024; s += 256) {
    int r = s >> 4, c4 = (s & 15) << 2;
    float4 v = make_float4(0.f, 0.f, 0.f, 0.f);
    if (r0 + r < n) v = *(const float4*)&X[(size_t)(r0 + r) * 64 + c4];
    Xs[r * 65 + c4 + 0] = v.x;
    Xs[r * 65 + c4 + 1] = v.y;
    Xs[r * 65 + c4 + 2] = v.z;
    Xs[r * 65 + c4 + 3] = v.w;
  }
  __syncthreads();
  int c4 = (t & 15) << 2;
  int rb = (t >> 4) << 2;
  float4 a0 = {0, 0, 0, 0}, a1 = {0, 0, 0, 0}, a2 = {0, 0, 0, 0}, a3 = {0, 0, 0, 0};
  for (int k = 0; k < 64; ++k) {
    float4 w = *(const float4*)&Ws[k * 64 + c4];
    float x0 = Xs[(rb + 0) * 65 + k];
    float x1 = Xs[(rb + 1) * 65 + k];
    float x2 = Xs[(rb + 2) * 65 + k];
    float x3 = Xs[(rb + 3) * 65 + k];
    a0.x += x0 * w.x; a0.y += x0 * w.y; a0.z += x0 * w.z; a0.w += x0 * w.w;
    a1.x += x1 * w.x; a1.y += x1 * w.y; a1.z += x1 * w.z; a1.w += x1 * w.w;
    a2.x += x2 * w.x; a2.y += x2 * w.y; a2.z += x2 * w.z; a2.w += x2 * w.w;
    a3.x += x3 * w.x; a3.y += x3 * w.y; a3.z += x3 * w.z; a3.w += x3 * w.w;
  }
  int r = r0 + rb;
  if (r + 0 < n) {
    float s0 = dinv[r + 0];
    a0.x *= s0; a0.y *= s0; a0.z *= s0; a0.w *= s0;
    *(float4*)&Y[(size_t)(r + 0) * 64 + c4] = a0;
  }
  if (r + 1 < n) {
    float s1 = dinv[r + 1];
    a1.x *= s1; a1.y *= s1; a1.z *= s1; a1.w *= s1;
    *(float4*)&Y[(size_t)(r + 1) * 64 + c4] = a1;
  }
  if (r + 2 < n) {
    float s2 = dinv[r + 2];
    a2.x *= s2; a2.y *= s2; a2.z *= s2; a2.w *= s2;
    *(float4*)&Y[(size_t)(r + 2) * 64 + c4] = a2;
  }
  if (r + 3 < n) {
    float s3 = dinv[r + 3];
    a3.x *= s3; a3.y *= s3; a3.z *= s3; a3.w *= s3;
    *(float4*)&Y[(size_t)(r + 3) * 64 + c4] = a3;
  }
}

// Aggregation: one wave per 16-dst task; 4 KB LDS acc; src-sorted sweep with
// double-buffered 16-gather pipeline (round r+1 in flight during round r's
// LDS accumulate). POOL=0: relu store; POOL=1: coalesced atomicAdd to gsum.
template <int POOL>
__global__ __launch_bounds__(256) void k_agg(
    const float* __restrict__ Hs, const int* __restrict__ csr,
    const int* __restrict__ blockBase, const float* __restrict__ dinv,
    const float* __restrict__ bias, const int* __restrict__ batch,
    float* __restrict__ outv, float* __restrict__ gsum, int n) {
  __shared__ float accs[4][16 * 64];  // 16 KB / block
  int t = threadIdx.x;
  int w = t >> 6, lane = t & 63;
  int task = blockIdx.x * 4 + w;
  int nodeBase = task << 4;
  if (nodeBase >= n) return;  // wave-uniform; no block syncs below
  float* a = accs[w];
#pragma unroll
  for (int d = 0; d < 16; ++d) a[d * 64 + lane] = 0.f;
  int p0 = blockBase[task];
  int p1 = blockBase[task + 1];
  int c = p1 - p0;
  if (c > 0) {
    int sub = lane & 15;
    int qlast = p1 - 1;
    auto ld = [&](int q) { return csr[q < qlast ? q : qlast]; };
    // readlane 16 indices from pk, zero tt, issue guarded gathers.
    auto gather16 = [&](int pk, int remN, int (&e)[16], float (&tt)[16]) {
#pragma unroll
      for (int j = 0; j < 16; ++j) e[j] = __builtin_amdgcn_readlane(pk, j);
#pragma unroll
      for (int j = 0; j < 16; ++j) tt[j] = 0.f;
      {
        tt[0] = Hs[(size_t)(e[0] >> 4) * 64 + lane];
        tt[1] = Hs[(size_t)(e[1] >> 4) * 64 + lane];
        tt[2] = Hs[(size_t)(e[2] >> 4) * 64 + lane];
        tt[3] = Hs[(size_t)(e[3] >> 4) * 64 + lane];
      }
      if (remN > 4) {
        tt[4] = Hs[(size_t)(e[4] >> 4) * 64 + lane];
        tt[5] = Hs[(size_t)(e[5] >> 4) * 64 + lane];
        tt[6] = Hs[(size_t)(e[6] >> 4) * 64 + lane];
        tt[7] = Hs[(size_t)(e[7] >> 4) * 64 + lane];
      }
      if (remN > 8) {
        tt[8] = Hs[(size_t)(e[8] >> 4) * 64 + lane];
        tt[9] = Hs[(size_t)(e[9] >> 4) * 64 + lane];
        tt[10] = Hs[(size_t)(e[10] >> 4) * 64 + lane];
        tt[11] = Hs[(size_t)(e[11] >> 4) * 64 + lane];
      }
      if (remN > 12) {
        tt[12] = Hs[(size_t)(e[12] >> 4) * 64 + lane];
        tt[13] = Hs[(size_t)(e[13] >> 4) * 64 + lane];
        tt[14] = Hs[(size_t)(e[14] >> 4) * 64 + lane];
        tt[15] = Hs[(size_t)(e[15] >> 4) * 64 + lane];
      }
    };
    // masked LDS accumulate (clamped duplicates are zeroed or masked).
    auto accum = [&](int (&e)[16], float (&tt)[16], int rc) {
      a[(e[0] & 15) * 64 + lane] += tt[0];
      if (1 < rc) a[(e[1] & 15) * 64 + lane] += tt[1];
      if (2 < rc) a[(e[2] & 15) * 64 + lane] += tt[2];
      if (3 < rc) a[(e[3] & 15) * 64 + lane] += tt[3];
      if (4 < rc) a[(e[4] & 15) * 64 + lane] += tt[4];
      if (5 < rc) a[(e[5] & 15) * 64 + lane] += tt[5];
      if (6 < rc) a[(e[6] & 15) * 64 + lane] += tt[6];
      if (7 < rc) a[(e[7] & 15) * 64 + lane] += tt[7];
      if (8 < rc) a[(e[8] & 15) * 64 + lane] += tt[8];
      if (9 < rc) a[(e[9] & 15) * 64 + lane] += tt[9];
      if (10 < rc) a[(e[10] & 15) * 64 + lane] += tt[10];
      if (11 < rc) a[(e[11] & 15) * 64 + lane] += tt[11];
      if (12 < rc) a[(e[12] & 15) * 64 + lane] += tt[12];
      if (13 < rc) a[(e[13] & 15) * 64 + lane] += tt[13];
      if (14 < rc) a[(e[14] & 15) * 64 + lane] += tt[14];
      if (15 < rc) a[(e[15] & 15) * 64 + lane] += tt[15];
    };
    int ecA[16], ecB[16];
    float tA[16], tB[16];
    int pkN = ld(p0 + sub);                           // idx round 0
    gather16(pkN, c, ecA, tA);                        // gathers round 0
    pkN = (c > 16) ? ld(p0 + 16 + sub) : 0;           // idx round 1
    int rb = 0;
    for (;;) {
      // stage A: round rb in tA; pkN = idx of round rb+16
      int remN = c - rb - 16;
      int pk2 = (remN > 16) ? ld(p0 + rb + 32 + sub) : 0;  // idx rb+32
      if (remN > 0) gather16(pkN, remN, ecB, tB);          // gathers rb+16
      accum(ecA, tA, c - rb);
      rb += 16;
      if (rb >= c) break;
      // stage B: round rb in tB; pk2 = idx of round rb+16
      remN = c - rb - 16;
      pkN = (remN > 16) ? ld(p0 + rb + 32 + sub) : 0;      // idx rb+32
      if (remN > 0) gather16(pk2, remN, ecA, tA);          // gathers rb+16
      accum(ecB, tB, c - rb);
      rb += 16;
      if (rb >= c) break;
    }
  }
  for (int d = 0; d < 16; ++d) {
    int node = nodeBase + d;
    if (node >= n) break;
    float dn = dinv[node];
    float v = a[d * 64 + lane] + Hs[(size_t)node * 64 + lane];
    v = v * dn + bias[lane];
    if (POOL) {
      int g = batch[node];
      atomicAdd(&gsum[(size_t)g * 64 + lane], v);
    } else {
      outv[(size_t)node * 64 + lane] = fmaxf(v, 0.f);
    }
  }
}

// Head: per-graph wave. Node count via binary search on sorted batch.
__global__ __launch_bounds__(256) void k_head(
    const float* __restrict__ gsum, const int* __restrict__ batch,
    const float* __restrict__ W3, const float* __restrict__ b3,
    const float* __restrict__ W4, const float* __restrict__ b4,
    float* __restrict__ out, int ng, int n) {
  int wid = (blockIdx.x * 256 + threadIdx.x) >> 6;
  int lane = threadIdx.x & 63;
  if (wid >= ng) return;
  int lo = 0, hi = n;
  while (lo < hi) {
    int mid = (lo + hi) >> 1;
    if (batch[mid] < wid) lo = mid + 1; else hi = mid;
  }
  int lb = lo;
  hi = n;
  while (lo < hi) {
    int mid = (lo + hi) >> 1;
    if (batch[mid] <= wid) lo = mid + 1; else hi = mid;
  }
  float cden = fmaxf((float)(lo - lb), 1.0f);
  float m = gsum[(size_t)wid * 64 + lane] / cden;
  float acc = b3[lane];
  for (int k = 0; k < 64; ++k) {
    float mk = __shfl(m, k);
    acc += mk * W3[k * 64 + lane];
  }
  acc = fmaxf(acc, 0.f);
  float r = acc * W4[lane];
  for (int off = 32; off; off >>= 1) r += __shfl_down(r, off);
  if (lane == 0) out[wid] = r + b4[0];
}

extern "C" void kernel_launch(void* const* d_in, const int* in_sizes, int n_in,
                              void* d_out, int out_size, void* d_ws, size_t ws_size,
                              hipStream_t stream) {
  const float* x = (const float*)d_in[0];
  const int* edge = (const int*)d_in[1];   // [2, E] int32
  const int* batch = (const int*)d_in[2];  // [N] int32, sorted
  const float* W1 = (const float*)d_in[3];
  const float* b1 = (const float*)d_in[4];
  const float* W2 = (const float*)d_in[5];
  const float* b2 = (const float*)d_in[6];
  const float* W3 = (const float*)d_in[7];
  const float* b3 = (const float*)d_in[8];
  const float* W4 = (const float*)d_in[9];
  const float* b4 = (const float*)d_in[10];
  float* out = (float*)d_out;

  const int n = in_sizes[0] / 64;   // 100000
  const int e = in_sizes[1] / 2;    // 1600000
  const int ng = out_size;          // 512
  const int* src = edge;
  const int* dst = edge + e;

  // Workspace layout.
  char* ws = (char*)d_ws;
  size_t off = 0;
  auto alloc = [&](size_t bytes) -> void* {
    void* p = ws + off;
    off = (off + bytes + 255) & ~(size_t)255;
    return p;
  };
  float* A = (float*)alloc((size_t)n * 64 * 4);   // Hs (scaled gemm output)
  float* B = (float*)alloc((size_t)n * 64 * 4);   // relu out; tmp during build
  float* dinv = (float*)alloc((size_t)n * 4);
  int* blockCnt = (int*)alloc(6400 * 4);
  int* blockBase = (int*)alloc(6400 * 4);
  int* blockCursor = (int*)alloc(6400 * 4);
  int* bucketCursor = (int*)alloc(128 * 4);
  int* csr = (int*)alloc((size_t)e * 4);
  float* gsum = (float*)alloc((size_t)ng * 64 * 4);
  int* tmp = (int*)B;  // build-time only; B not live yet

  const int nblk = (n + 15) / 16;        // 6250 dst-blocks (16 nodes each)
  const int nbuck = (nblk + 63) / 64;    // 98 coarse buckets (1024 nodes)
  const int nagg = (nblk + 3) / 4;       // agg workgroups (1563)
  const int gsz = ng * 64;

  int zmax = gsz > 6400 ? gsz : 6400;
  k_init<<<(zmax + 255) / 256, 256, 0, stream>>>(gsum, blockCnt, gsz, 6400);
  k_histB<<<(e + 8191) / 8192, 256, 0, stream>>>(dst, blockCnt, e, nblk);
  k_scan<<<1, 256, 0, stream>>>(blockCnt, blockBase, blockCursor, bucketCursor,
                                nblk, nbuck);
  k_p1<<<(e + 2047) / 2048, 256, 0, stream>>>(src, dst, bucketCursor, tmp, e,
                                              nbuck);
  k_p2<<<nbuck * 8, 256, 0, stream>>>(blockBase, tmp, blockCursor, csr, nblk);
  k_bsort<<<nblk, 256, 0, stream>>>(blockBase, csr, dinv, n);

  // Layer 1: A = (x@W1)*dinv ; B = relu(agg(A)*dinv + b1)
  k_gemm64s<<<(n + 63) / 64, 256, 0, stream>>>(x, W1, dinv, A, n);
  k_agg<0><<<nagg, 256, 0, stream>>>(A, csr, blockBase, dinv, b1, batch, B, gsum, n);
  // Layer 2: A = (B@W2)*dinv ; pool(agg(A)*dinv + b2)
  k_gemm64s<<<(n + 63) / 64, 256, 0, stream>>>(B, W2, dinv, A, n);
  k_agg<1><<<nagg, 256, 0, stream>>>(A, csr, blockBase, dinv, b2, batch, B, gsum, n);
  // Head
  k_head<<<((size_t)ng * 64 + 255) / 256, 256, 0, stream>>>(gsum, batch, W3, b3,
                                                            W4, b4, out, ng, n);
}